// Round 23
// baseline (477.988 us; speedup 1.0000x reference)
//
#include <hip/hip_runtime.h>

#define B_   64
#define C_   256
#define D_   128
#define HW_  1024
#define K_   1024
#define N_   65536
#define MARGIN_PREF 1.2e-3f

typedef __attribute__((ext_vector_type(8))) short short8;
typedef __attribute__((ext_vector_type(4))) float f32x4;

__device__ __forceinline__ unsigned short f2bf(float f) {   // RNE f32->bf16
    unsigned u = __float_as_uint(f);
    return (unsigned short)((u + 0x7FFFu + ((u >> 16) & 1u)) >> 16);
}
__device__ __forceinline__ unsigned long long packdk(float d, int k) {  // order-preserving
    unsigned u = __float_as_uint(d);
    u = (u & 0x80000000u) ? ~u : (u | 0x80000000u);
    return ((unsigned long long)u << 10) | (unsigned)k;
}
__device__ __forceinline__ unsigned long long min64(unsigned long long a, unsigned long long b) {
    return a < b ? a : b;
}

// numpy pairwise-sum emulation, n=128 — scalar 8-accumulator tree (verified R4-R22)
template <typename F>
__device__ __forceinline__ float np_sum128(F ld) {
#pragma clang fp contract(off)
    float r0 = ld(0), r1 = ld(1), r2 = ld(2), r3 = ld(3);
    float r4 = ld(4), r5 = ld(5), r6 = ld(6), r7 = ld(7);
#pragma unroll
    for (int i = 8; i < 128; i += 8) {
        r0 = r0 + ld(i + 0); r1 = r1 + ld(i + 1);
        r2 = r2 + ld(i + 2); r3 = r3 + ld(i + 3);
        r4 = r4 + ld(i + 4); r5 = r5 + ld(i + 5);
        r6 = r6 + ld(i + 6); r7 = r7 + ld(i + 7);
    }
    return ((r0 + r1) + (r2 + r3)) + ((r4 + r5) + (r6 + r7));
}

// ---------------- K0: enorm (np bins) + embed -> bf16, PRE-SWIZZLED rows ----------------
__global__ __launch_bounds__(256) void k0_norms(const float* __restrict__ embed,
                                                float* __restrict__ enorm,
                                                unsigned short* __restrict__ ebf) {
#pragma clang fp contract(off)
    int k = blockIdx.x * 256 + threadIdx.x;
    if (k >= K_) return;
    const float* e = embed + (size_t)k * D_;
    enorm[k] = np_sum128([&](int i) { float v = e[i]; return v * v; });
    const int sw = (k & 7) << 4;
    char* rowp = (char*)ebf + ((size_t)k << 8);
#pragma unroll
    for (int j = 0; j < 16; ++j) {            // 16B chunks, swizzle preserves chunks
        short8 v;
#pragma unroll
        for (int q = 0; q < 8; ++q) v[q] = (short)f2bf(e[j * 8 + q]);
        *(short8*)(rowp + ((j * 16) ^ sw)) = v;
    }
}

// ---------------- K1: einsum-f32 emulation + bf16 copy + FUSED znorm ----------------
__global__ __launch_bounds__(256) void k1_proj(const float* __restrict__ z,
                                               const float* __restrict__ w,
                                               const float* __restrict__ bias,
                                               float* __restrict__ zp,
                                               unsigned short* __restrict__ zbf,
                                               float* __restrict__ znorm) {
#pragma clang fp contract(off)
    __shared__ float smem1[64 * 64 + 64 * 128];    // zs(16KB) + wsh(32KB); later aliased
    float (*zs)[64]   = (float(*)[64])smem1;
    float (*wsh)[128] = (float(*)[128])(smem1 + 4096);
    const int b   = blockIdx.x >> 4;
    const int hw0 = (blockIdx.x & 15) << 6;
    const int t   = threadIdx.x;
    const int hwg = (t & 7) * 8;
    const int dg  = (t >> 3) * 4;

    float acc[8][4];
#pragma unroll
    for (int i = 0; i < 8; ++i)
#pragma unroll
        for (int j = 0; j < 4; ++j) acc[i][j] = 0.f;

    for (int ct = 0; ct < C_; ct += 64) {
        __syncthreads();
#pragma unroll
        for (int i = 0; i < 16; ++i) {
            int idx = i * 256 + t;
            int cc = idx >> 6, hwl = idx & 63;
            zs[cc][hwl] = z[(((size_t)b * C_ + ct + cc) << 10) + hw0 + hwl];
        }
#pragma unroll
        for (int i = 0; i < 32; ++i) {
            int idx = i * 256 + t;
            int cc = idx >> 7, d = idx & 127;
            wsh[cc][d] = w[(size_t)d * C_ + ct + cc];
        }
        __syncthreads();
#pragma unroll 2
        for (int cc = 0; cc < 64; ++cc) {       // c strictly ascending across ct blocks
            float4 za = *(const float4*)&zs[cc][hwg];
            float4 zb = *(const float4*)&zs[cc][hwg + 4];
            float4 wv = *(const float4*)&wsh[cc][dg];
            float zv[8]  = {za.x, za.y, za.z, za.w, zb.x, zb.y, zb.z, zb.w};
            float wva[4] = {wv.x, wv.y, wv.z, wv.w};
#pragma unroll
            for (int i = 0; i < 8; ++i)
#pragma unroll
                for (int j = 0; j < 4; ++j) {
                    float p = zv[i] * wva[j];    // round mul
                    acc[i][j] = acc[i][j] + p;   // round add (no contraction)
                }
        }
    }
    float vv[8][4];
#pragma unroll
    for (int i = 0; i < 8; ++i)
#pragma unroll
        for (int j = 0; j < 4; ++j) {
            float v = acc[i][j] + bias[dg + j];
            size_t off = (((size_t)b * HW_ + hw0 + hwg + i) << 7) + dg + j;
            zp[off]  = v;
            zbf[off] = f2bf(v);
            vv[i][j] = v;
        }

    // ---- fused znorm: stage the block's 64 complete rows, np scalar-8 tree ----
    __syncthreads();                               // zs/wsh reads all done
    float (*ztile)[129] = (float(*)[129])smem1;    // 64x129 = 8256 floats, fits
#pragma unroll
    for (int i = 0; i < 8; ++i)
#pragma unroll
        for (int j = 0; j < 4; ++j)
            ztile[hwg + i][dg + j] = vv[i][j];
    __syncthreads();
    if (t < 64)
        znorm[(size_t)b * HW_ + hw0 + t] =
            np_sum128([&](int i) { float v2 = ztile[t][i]; return v2 * v2; });
}

// ---------------- K2: GEMM-shaped two-pass MFMA prefilter + exact np-bin rescue
//                      + FUSED gather/NCHW-transpose epilogue ----------------
// Core loop byte-identical to R22 (best known: 219us). After phase C, kk is
// broadcast via LDS and the block writes its own out0 tiles (k3 eliminated).
__global__ __launch_bounds__(256) void k2_argmin(const unsigned short* __restrict__ zbf,
                                                 const unsigned short* __restrict__ ebf,
                                                 const float* __restrict__ zp,
                                                 const float* __restrict__ embed,
                                                 const float* __restrict__ enorm,
                                                 const float* __restrict__ znorm,
                                                 float* __restrict__ out0,
                                                 float* __restrict__ out_idx) {
    __shared__ __align__(16) char smem[36864];     // passes: etile 2x16KB + els 4KB
    __shared__ int kks[128];                       // gather: aliased tile 64x132 f32
    unsigned char (*etile)[16384] = (unsigned char(*)[16384])smem;
    float* els = (float*)(smem + 32768);
    const int t   = threadIdx.x;
    const int l   = t & 63;
    const int wid = t >> 6;                        // 0..3
    const int rb  = blockIdx.x * 128;              // block's first row
    const int r0  = rb + wid * 32;                 // wave's 32 rows (2 row-frags)
    const int lr  = l & 15;
    const int lh  = l >> 4;

    // z fragments (B operand): 2 row-frags x 4 d-tiles (R9-proven shape)
    short8 zfrag[2][4];
#pragma unroll
    for (int rt = 0; rt < 2; ++rt)
#pragma unroll
        for (int dt = 0; dt < 4; ++dt)
            zfrag[rt][dt] = *(const short8*)(zbf + (((size_t)(r0 + rt * 16 + lr)) << 7) + dt * 32 + lh * 8);

    // per-lane swizzled ds_read offsets
    const int swz = (lr & 7) << 4;
    int roff[4];
#pragma unroll
    for (int dt = 0; dt < 4; ++dt)
        roff[dt] = lr * 256 + ((dt * 64 + lh * 16) ^ swz);

    const char* ebf_b = (const char*)ebf;
    auto STAGE = [&](int st, int b) {              // async 16KB k-step tile -> LDS
#pragma unroll
        for (int j = 0; j < 4; ++j) {
            int off = j * 4096 + (t << 4);
            __builtin_amdgcn_global_load_lds(
                (const __attribute__((address_space(1))) void*)(ebf_b + ((size_t)st << 14) + off),
                (__attribute__((address_space(3))) void*)(&etile[b][off]),
                16, 0, 0);
        }
    };

    // stage enorm to LDS (coalesced, once)
#pragma unroll
    for (int i = 0; i < 4; ++i) els[i * 256 + t] = enorm[i * 256 + t];

    // ---- Pass A: f32 running MIN per row-frag (branch-free, no k-tracking) ----
    float bmin0 = 1e30f, bmin1 = 1e30f;
    STAGE(0, 0);
#pragma unroll 1
    for (int st = 0; st < 16; ++st) {
        __syncthreads();
        if (st < 15) STAGE(st + 1, (st + 1) & 1);
        const unsigned char* buf = etile[st & 1];
#pragma unroll
        for (int kf = 0; kf < 4; ++kf) {
            short8 af[4];
#pragma unroll
            for (int dt = 0; dt < 4; ++dt)
                af[dt] = *(const short8*)(buf + kf * 4096 + roff[dt]);
            f32x4 en4 = *(const f32x4*)(els + st * 64 + kf * 16 + lh * 4);
            f32x4 a0 = {0.f, 0.f, 0.f, 0.f};
            f32x4 a1 = {0.f, 0.f, 0.f, 0.f};
#pragma unroll
            for (int dt = 0; dt < 4; ++dt)
                a0 = __builtin_amdgcn_mfma_f32_16x16x32_bf16(af[dt], zfrag[0][dt], a0, 0, 0, 0);
#pragma unroll
            for (int dt = 0; dt < 4; ++dt)
                a1 = __builtin_amdgcn_mfma_f32_16x16x32_bf16(af[dt], zfrag[1][dt], a1, 0, 0, 0);
#pragma unroll
            for (int reg = 0; reg < 4; ++reg) {
                bmin0 = fminf(bmin0, fmaf(-2.f, a0[reg], en4[reg]));
                bmin1 = fminf(bmin1, fmaf(-2.f, a1[reg], en4[reg]));
            }
        }
    }
    {
        bmin0 = fminf(bmin0, __shfl_xor(bmin0, 16, 64));
        bmin0 = fminf(bmin0, __shfl_xor(bmin0, 32, 64));
        bmin1 = fminf(bmin1, __shfl_xor(bmin1, 16, 64));
        bmin1 = fminf(bmin1, __shfl_xor(bmin1, 32, 64));
    }
    const float thr0 = bmin0 + MARGIN_PREF;
    const float thr1 = bmin1 + MARGIN_PREF;

    // ---- Pass B: bitwise-identical recompute, collect candidates ----
    unsigned long long ca0 = 0, cb0 = 0, ca1 = 0, cb1 = 0;
    int cnt0 = 0, cnt1 = 0;
    __syncthreads();
    STAGE(0, 0);
#pragma unroll 1
    for (int st = 0; st < 16; ++st) {
        __syncthreads();
        if (st < 15) STAGE(st + 1, (st + 1) & 1);
        const unsigned char* buf = etile[st & 1];
#pragma unroll
        for (int kf = 0; kf < 4; ++kf) {
            short8 af[4];
#pragma unroll
            for (int dt = 0; dt < 4; ++dt)
                af[dt] = *(const short8*)(buf + kf * 4096 + roff[dt]);
            f32x4 en4 = *(const f32x4*)(els + st * 64 + kf * 16 + lh * 4);
            f32x4 a0 = {0.f, 0.f, 0.f, 0.f};
            f32x4 a1 = {0.f, 0.f, 0.f, 0.f};
#pragma unroll
            for (int dt = 0; dt < 4; ++dt)
                a0 = __builtin_amdgcn_mfma_f32_16x16x32_bf16(af[dt], zfrag[0][dt], a0, 0, 0, 0);
#pragma unroll
            for (int dt = 0; dt < 4; ++dt)
                a1 = __builtin_amdgcn_mfma_f32_16x16x32_bf16(af[dt], zfrag[1][dt], a1, 0, 0, 0);
#pragma unroll
            for (int reg = 0; reg < 4; ++reg) {
                int kk = st * 64 + kf * 16 + lh * 4 + reg;
                float d0 = fmaf(-2.f, a0[reg], en4[reg]);
                if (d0 < thr0) {
                    if (cnt0 < 6)       ca0 |= (unsigned long long)kk << (10 * cnt0);
                    else if (cnt0 < 12) cb0 |= (unsigned long long)kk << (10 * (cnt0 - 6));
                    ++cnt0;
                }
                float d1 = fmaf(-2.f, a1[reg], en4[reg]);
                if (d1 < thr1) {
                    if (cnt1 < 6)       ca1 |= (unsigned long long)kk << (10 * cnt1);
                    else if (cnt1 < 12) cb1 |= (unsigned long long)kk << (10 * (cnt1 - 6));
                    ++cnt1;
                }
            }
        }
    }

    // ---- Phase C: exact np-bin refine of candidates (R4-verified chain) ----
    unsigned long long fin[2];
#pragma unroll
    for (int rt = 0; rt < 2; ++rt) {
        const int myrow = r0 + rt * 16 + lr;
        const float* zrow = zp + ((size_t)myrow << 7);
        const float  zn   = znorm[myrow];
        unsigned long long best = ~0ull;
        unsigned long long ca = rt == 0 ? ca0 : ca1, cb = rt == 0 ? cb0 : cb1;
        int cnt = rt == 0 ? cnt0 : cnt1;

        auto refine = [&](int kk) {
#pragma clang fp contract(off)
            const float* e = embed + ((size_t)kk << 7);
            float s = 0.f;
#pragma unroll 1
            for (int d = 0; d < 128; ++d) s = fmaf(zrow[d], e[d], s);
            float T  = 2.0f * s;
            float A  = zn - T;                  // bin-maker 1 (mag ~13)
            float Bv = A + enorm[kk];           // bin-maker 2
            best = min64(best, packdk(Bv, kk)); // lex (bin, k) = np first-occurrence
        };

        if (cnt <= 12) {
#pragma unroll
            for (int i = 0; i < 6; ++i)
                if (i < cnt) refine((int)((ca >> (10 * i)) & 1023ull));
#pragma unroll
            for (int i = 6; i < 12; ++i)
                if (i < cnt) refine((int)((cb >> (10 * (i - 6))) & 1023ull));
        } else {                                // overflow fallback: lane's k-subset
#pragma unroll 1
            for (int st = 0; st < 16; ++st)
#pragma unroll
                for (int kf = 0; kf < 4; ++kf)
#pragma unroll
                    for (int reg = 0; reg < 4; ++reg)
                        refine(st * 64 + kf * 16 + lh * 4 + reg);
        }
        unsigned long long o;
        o = __shfl_xor(best, 16, 64); best = min64(best, o);
        o = __shfl_xor(best, 32, 64); best = min64(best, o);
        fin[rt] = best;
    }

    // publish indices + kk broadcast for the fused gather
    if (l < 16) {
#pragma unroll
        for (int rt = 0; rt < 2; ++rt) {
            int kk = (int)(fin[rt] & 1023ull);
            kks[wid * 32 + rt * 16 + l] = kk;
            out_idx[r0 + rt * 16 + l]   = (float)kk;
        }
    }
    __syncthreads();                               // kks ready; etile/els dead

    // ---- fused k3: gather + NCHW transpose for this block's 128 rows ----
    float (*gtile)[132] = (float(*)[132])smem;     // 64x132 f32 = 33792B <= 36864
    const int bb  = rb >> 10;
    const int hw0 = rb & 1023;
#pragma unroll 1
    for (int sub = 0; sub < 2; ++sub) {
#pragma unroll
        for (int i = 0; i < 32; ++i) {
            int idx = i * 256 + t;
            int hwl = idx >> 7, d = idx & 127;
            gtile[hwl][d] = embed[(size_t)kks[sub * 64 + hwl] * 128 + d];
        }
        __syncthreads();
#pragma unroll
        for (int i = 0; i < 32; ++i) {
            int idx = i * 256 + t;
            int d = idx >> 6, hwl = idx & 63;
            out0[(((size_t)bb * D_ + d) << 10) + hw0 + sub * 64 + hwl] = gtile[hwl][d];
        }
        __syncthreads();
    }
}

extern "C" void kernel_launch(void* const* d_in, const int* in_sizes, int n_in,
                              void* d_out, int out_size, void* d_ws, size_t ws_size,
                              hipStream_t stream) {
    const float* z     = (const float*)d_in[0];
    const float* pw    = (const float*)d_in[1];
    const float* pb    = (const float*)d_in[2];
    const float* embed = (const float*)d_in[3];

    float* out0 = (float*)d_out;
    float* out1 = (float*)d_out + (size_t)B_ * D_ * HW_;

    char* ws = (char*)d_ws;
    float*          zp    = (float*)ws;                                   // 32 MB
    unsigned short* zbf   = (unsigned short*)(ws + (32u << 20));          // 16 MB
    unsigned short* ebf   = (unsigned short*)(ws + (48u << 20));          // 256 KB
    float*          enorm = (float*)(ws + (48u << 20) + (256u << 10));    // 4 KB
    float*          znorm = (float*)(ws + (49u << 20));                   // 256 KB

    hipLaunchKernelGGL(k0_norms,  dim3(4),    dim3(256), 0, stream, embed, enorm, ebf);
    hipLaunchKernelGGL(k1_proj,   dim3(1024), dim3(256), 0, stream, z, pw, pb, zp, zbf, znorm);
    hipLaunchKernelGGL(k2_argmin, dim3(512),  dim3(256), 0, stream,
                       zbf, ebf, zp, embed, enorm, znorm, out0, out1);
}

// Round 24
// 365.708 us; speedup vs baseline: 1.3070x; 1.3070x over previous
//
#include <hip/hip_runtime.h>

#define B_   64
#define C_   256
#define D_   128
#define HW_  1024
#define K_   1024
#define N_   65536
#define MARGIN_PREF 1.2e-3f

typedef __attribute__((ext_vector_type(8))) short short8;
typedef __attribute__((ext_vector_type(4))) float f32x4;

__device__ __forceinline__ unsigned short f2bf(float f) {   // RNE f32->bf16
    unsigned u = __float_as_uint(f);
    return (unsigned short)((u + 0x7FFFu + ((u >> 16) & 1u)) >> 16);
}
__device__ __forceinline__ unsigned long long packdk(float d, int k) {  // order-preserving
    unsigned u = __float_as_uint(d);
    u = (u & 0x80000000u) ? ~u : (u | 0x80000000u);
    return ((unsigned long long)u << 10) | (unsigned)k;
}
__device__ __forceinline__ unsigned long long min64(unsigned long long a, unsigned long long b) {
    return a < b ? a : b;
}

// numpy pairwise-sum emulation, n=128 — scalar 8-accumulator tree (verified R4-R23)
template <typename F>
__device__ __forceinline__ float np_sum128(F ld) {
#pragma clang fp contract(off)
    float r0 = ld(0), r1 = ld(1), r2 = ld(2), r3 = ld(3);
    float r4 = ld(4), r5 = ld(5), r6 = ld(6), r7 = ld(7);
#pragma unroll
    for (int i = 8; i < 128; i += 8) {
        r0 = r0 + ld(i + 0); r1 = r1 + ld(i + 1);
        r2 = r2 + ld(i + 2); r3 = r3 + ld(i + 3);
        r4 = r4 + ld(i + 4); r5 = r5 + ld(i + 5);
        r6 = r6 + ld(i + 6); r7 = r7 + ld(i + 7);
    }
    return ((r0 + r1) + (r2 + r3)) + ((r4 + r5) + (r6 + r7));
}

// ---------------- K0: enorm (np bins) + embed -> bf16, PRE-SWIZZLED rows ----------------
__global__ __launch_bounds__(256) void k0_norms(const float* __restrict__ embed,
                                                float* __restrict__ enorm,
                                                unsigned short* __restrict__ ebf) {
#pragma clang fp contract(off)
    int k = blockIdx.x * 256 + threadIdx.x;
    if (k >= K_) return;
    const float* e = embed + (size_t)k * D_;
    enorm[k] = np_sum128([&](int i) { float v = e[i]; return v * v; });
    const int sw = (k & 7) << 4;
    char* rowp = (char*)ebf + ((size_t)k << 8);
#pragma unroll
    for (int j = 0; j < 16; ++j) {            // 16B chunks, swizzle preserves chunks
        short8 v;
#pragma unroll
        for (int q = 0; q < 8; ++q) v[q] = (short)f2bf(e[j * 8 + q]);
        *(short8*)(rowp + ((j * 16) ^ sw)) = v;
    }
}

// ---------------- K1: einsum-f32 emulation + bf16 copy + FUSED znorm (R23-proven) ----------------
__global__ __launch_bounds__(256) void k1_proj(const float* __restrict__ z,
                                               const float* __restrict__ w,
                                               const float* __restrict__ bias,
                                               float* __restrict__ zp,
                                               unsigned short* __restrict__ zbf,
                                               float* __restrict__ znorm) {
#pragma clang fp contract(off)
    __shared__ float smem1[64 * 64 + 64 * 128];    // zs(16KB) + wsh(32KB); later aliased
    float (*zs)[64]   = (float(*)[64])smem1;
    float (*wsh)[128] = (float(*)[128])(smem1 + 4096);
    const int b   = blockIdx.x >> 4;
    const int hw0 = (blockIdx.x & 15) << 6;
    const int t   = threadIdx.x;
    const int hwg = (t & 7) * 8;
    const int dg  = (t >> 3) * 4;

    float acc[8][4];
#pragma unroll
    for (int i = 0; i < 8; ++i)
#pragma unroll
        for (int j = 0; j < 4; ++j) acc[i][j] = 0.f;

    for (int ct = 0; ct < C_; ct += 64) {
        __syncthreads();
#pragma unroll
        for (int i = 0; i < 16; ++i) {
            int idx = i * 256 + t;
            int cc = idx >> 6, hwl = idx & 63;
            zs[cc][hwl] = z[(((size_t)b * C_ + ct + cc) << 10) + hw0 + hwl];
        }
#pragma unroll
        for (int i = 0; i < 32; ++i) {
            int idx = i * 256 + t;
            int cc = idx >> 7, d = idx & 127;
            wsh[cc][d] = w[(size_t)d * C_ + ct + cc];
        }
        __syncthreads();
#pragma unroll 2
        for (int cc = 0; cc < 64; ++cc) {       // c strictly ascending across ct blocks
            float4 za = *(const float4*)&zs[cc][hwg];
            float4 zb = *(const float4*)&zs[cc][hwg + 4];
            float4 wv = *(const float4*)&wsh[cc][dg];
            float zv[8]  = {za.x, za.y, za.z, za.w, zb.x, zb.y, zb.z, zb.w};
            float wva[4] = {wv.x, wv.y, wv.z, wv.w};
#pragma unroll
            for (int i = 0; i < 8; ++i)
#pragma unroll
                for (int j = 0; j < 4; ++j) {
                    float p = zv[i] * wva[j];    // round mul
                    acc[i][j] = acc[i][j] + p;   // round add (no contraction)
                }
        }
    }
    float vv[8][4];
#pragma unroll
    for (int i = 0; i < 8; ++i)
#pragma unroll
        for (int j = 0; j < 4; ++j) {
            float v = acc[i][j] + bias[dg + j];
            size_t off = (((size_t)b * HW_ + hw0 + hwg + i) << 7) + dg + j;
            zp[off]  = v;
            zbf[off] = f2bf(v);
            vv[i][j] = v;
        }

    // ---- fused znorm: stage the block's 64 complete rows, np scalar-8 tree ----
    __syncthreads();                               // zs/wsh reads all done
    float (*ztile)[129] = (float(*)[129])smem1;    // 64x129 = 8256 floats, fits
#pragma unroll
    for (int i = 0; i < 8; ++i)
#pragma unroll
        for (int j = 0; j < 4; ++j)
            ztile[hwg + i][dg + j] = vv[i][j];
    __syncthreads();
    if (t < 64)
        znorm[(size_t)b * HW_ + hw0 + t] =
            np_sum128([&](int i) { float v2 = ztile[t][i]; return v2 * v2; });
}

// ---------------- K2: GEMM-shaped two-pass MFMA prefilter + exact np-bin rescue ----------------
// R22's kernel byte-identical (best known: 219us, VGPR 56, no fused epilogue).
__global__ __launch_bounds__(256) void k2_argmin(const unsigned short* __restrict__ zbf,
                                                 const unsigned short* __restrict__ ebf,
                                                 const float* __restrict__ zp,
                                                 const float* __restrict__ embed,
                                                 const float* __restrict__ enorm,
                                                 const float* __restrict__ znorm,
                                                 int* __restrict__ bestk_ws,
                                                 float* __restrict__ out_idx) {
    __shared__ unsigned char etile[2][64 * 256];   // dbuf 16KB: 64 k-rows x 256B (pre-swizzled)
    __shared__ float els[1024];                    // enorm, block-resident
    const int t   = threadIdx.x;
    const int l   = t & 63;
    const int wid = t >> 6;                        // 0..3
    const int r0  = blockIdx.x * 128 + wid * 32;   // wave's 32 rows (2 row-frags)
    const int lr  = l & 15;
    const int lh  = l >> 4;

    // z fragments (B operand): 2 row-frags x 4 d-tiles (R9-proven shape)
    short8 zfrag[2][4];
#pragma unroll
    for (int rt = 0; rt < 2; ++rt)
#pragma unroll
        for (int dt = 0; dt < 4; ++dt)
            zfrag[rt][dt] = *(const short8*)(zbf + (((size_t)(r0 + rt * 16 + lr)) << 7) + dt * 32 + lh * 8);

    // per-lane swizzled ds_read offsets (e-row lr within 16-k frag, col dt*64+lh*16)
    const int swz = (lr & 7) << 4;
    int roff[4];
#pragma unroll
    for (int dt = 0; dt < 4; ++dt)
        roff[dt] = lr * 256 + ((dt * 64 + lh * 16) ^ swz);

    const char* ebf_b = (const char*)ebf;
    auto STAGE = [&](int st, int b) {              // async 16KB k-step tile -> LDS
#pragma unroll
        for (int j = 0; j < 4; ++j) {
            int off = j * 4096 + (t << 4);
            __builtin_amdgcn_global_load_lds(
                (const __attribute__((address_space(1))) void*)(ebf_b + ((size_t)st << 14) + off),
                (__attribute__((address_space(3))) void*)(&etile[b][off]),
                16, 0, 0);
        }
    };

    // stage enorm to LDS (coalesced, once)
#pragma unroll
    for (int i = 0; i < 4; ++i) els[i * 256 + t] = enorm[i * 256 + t];

    // ---- Pass A: f32 running MIN per row-frag (branch-free, no k-tracking) ----
    float bmin0 = 1e30f, bmin1 = 1e30f;
    STAGE(0, 0);
#pragma unroll 1
    for (int st = 0; st < 16; ++st) {
        __syncthreads();                           // drains stage(st) (+ els first time)
        if (st < 15) STAGE(st + 1, (st + 1) & 1);
        const unsigned char* buf = etile[st & 1];
#pragma unroll
        for (int kf = 0; kf < 4; ++kf) {
            short8 af[4];
#pragma unroll
            for (int dt = 0; dt < 4; ++dt)
                af[dt] = *(const short8*)(buf + kf * 4096 + roff[dt]);
            f32x4 en4 = *(const f32x4*)(els + st * 64 + kf * 16 + lh * 4);
            f32x4 a0 = {0.f, 0.f, 0.f, 0.f};
            f32x4 a1 = {0.f, 0.f, 0.f, 0.f};
#pragma unroll
            for (int dt = 0; dt < 4; ++dt)
                a0 = __builtin_amdgcn_mfma_f32_16x16x32_bf16(af[dt], zfrag[0][dt], a0, 0, 0, 0);
#pragma unroll
            for (int dt = 0; dt < 4; ++dt)
                a1 = __builtin_amdgcn_mfma_f32_16x16x32_bf16(af[dt], zfrag[1][dt], a1, 0, 0, 0);
#pragma unroll
            for (int reg = 0; reg < 4; ++reg) {
                bmin0 = fminf(bmin0, fmaf(-2.f, a0[reg], en4[reg]));
                bmin1 = fminf(bmin1, fmaf(-2.f, a1[reg], en4[reg]));
            }
        }
    }
    {   // row-min across lanes {lr, lr+16, lr+32, lr+48}
        bmin0 = fminf(bmin0, __shfl_xor(bmin0, 16, 64));
        bmin0 = fminf(bmin0, __shfl_xor(bmin0, 32, 64));
        bmin1 = fminf(bmin1, __shfl_xor(bmin1, 16, 64));
        bmin1 = fminf(bmin1, __shfl_xor(bmin1, 32, 64));
    }
    const float thr0 = bmin0 + MARGIN_PREF;
    const float thr1 = bmin1 + MARGIN_PREF;

    // ---- Pass B: bitwise-identical recompute, collect candidates (R9-proven form) ----
    unsigned long long ca0 = 0, cb0 = 0, ca1 = 0, cb1 = 0;
    int cnt0 = 0, cnt1 = 0;
    __syncthreads();
    STAGE(0, 0);
#pragma unroll 1
    for (int st = 0; st < 16; ++st) {
        __syncthreads();
        if (st < 15) STAGE(st + 1, (st + 1) & 1);
        const unsigned char* buf = etile[st & 1];
#pragma unroll
        for (int kf = 0; kf < 4; ++kf) {
            short8 af[4];
#pragma unroll
            for (int dt = 0; dt < 4; ++dt)
                af[dt] = *(const short8*)(buf + kf * 4096 + roff[dt]);
            f32x4 en4 = *(const f32x4*)(els + st * 64 + kf * 16 + lh * 4);
            f32x4 a0 = {0.f, 0.f, 0.f, 0.f};
            f32x4 a1 = {0.f, 0.f, 0.f, 0.f};
#pragma unroll
            for (int dt = 0; dt < 4; ++dt)
                a0 = __builtin_amdgcn_mfma_f32_16x16x32_bf16(af[dt], zfrag[0][dt], a0, 0, 0, 0);
#pragma unroll
            for (int dt = 0; dt < 4; ++dt)
                a1 = __builtin_amdgcn_mfma_f32_16x16x32_bf16(af[dt], zfrag[1][dt], a1, 0, 0, 0);
#pragma unroll
            for (int reg = 0; reg < 4; ++reg) {
                int kk = st * 64 + kf * 16 + lh * 4 + reg;
                float d0 = fmaf(-2.f, a0[reg], en4[reg]);
                if (d0 < thr0) {
                    if (cnt0 < 6)       ca0 |= (unsigned long long)kk << (10 * cnt0);
                    else if (cnt0 < 12) cb0 |= (unsigned long long)kk << (10 * (cnt0 - 6));
                    ++cnt0;
                }
                float d1 = fmaf(-2.f, a1[reg], en4[reg]);
                if (d1 < thr1) {
                    if (cnt1 < 6)       ca1 |= (unsigned long long)kk << (10 * cnt1);
                    else if (cnt1 < 12) cb1 |= (unsigned long long)kk << (10 * (cnt1 - 6));
                    ++cnt1;
                }
            }
        }
    }

    // ---- Phase C: exact np-bin refine of candidates (R4-verified chain) ----
    unsigned long long fin[2];
#pragma unroll
    for (int rt = 0; rt < 2; ++rt) {
        const int myrow = r0 + rt * 16 + lr;
        const float* zrow = zp + ((size_t)myrow << 7);
        const float  zn   = znorm[myrow];
        unsigned long long best = ~0ull;
        unsigned long long ca = rt == 0 ? ca0 : ca1, cb = rt == 0 ? cb0 : cb1;
        int cnt = rt == 0 ? cnt0 : cnt1;

        auto refine = [&](int kk) {
#pragma clang fp contract(off)
            const float* e = embed + ((size_t)kk << 7);
            float s = 0.f;
#pragma unroll 1
            for (int d = 0; d < 128; ++d) s = fmaf(zrow[d], e[d], s);
            float T  = 2.0f * s;
            float A  = zn - T;                  // bin-maker 1 (mag ~13)
            float Bv = A + enorm[kk];           // bin-maker 2
            best = min64(best, packdk(Bv, kk)); // lex (bin, k) = np first-occurrence
        };

        if (cnt <= 12) {
#pragma unroll
            for (int i = 0; i < 6; ++i)
                if (i < cnt) refine((int)((ca >> (10 * i)) & 1023ull));
#pragma unroll
            for (int i = 6; i < 12; ++i)
                if (i < cnt) refine((int)((cb >> (10 * (i - 6))) & 1023ull));
        } else {                                // overflow fallback: lane's k-subset
#pragma unroll 1
            for (int st = 0; st < 16; ++st)
#pragma unroll
                for (int kf = 0; kf < 4; ++kf)
#pragma unroll
                    for (int reg = 0; reg < 4; ++reg)
                        refine(st * 64 + kf * 16 + lh * 4 + reg);
        }
        unsigned long long o;
        o = __shfl_xor(best, 16, 64); best = min64(best, o);
        o = __shfl_xor(best, 32, 64); best = min64(best, o);
        fin[rt] = best;
    }

    if (l < 16) {
#pragma unroll
        for (int rt = 0; rt < 2; ++rt) {
            int row = r0 + rt * 16 + l;
            int kk  = (int)(fin[rt] & 1023ull);
            bestk_ws[row] = kk;
            out_idx[row]  = (float)kk;
        }
    }
}

// ---------------- K3: gather + NCHW transpose (R22-proven) ----------------
__global__ __launch_bounds__(256) void k3_gather(const float* __restrict__ embed,
                                                 const int* __restrict__ bestk,
                                                 float* __restrict__ out0) {
    __shared__ float tile[64][129];
    const int b   = blockIdx.x >> 4;
    const int hw0 = (blockIdx.x & 15) << 6;
    const int t   = threadIdx.x;
    const int n0  = b * HW_ + hw0;
#pragma unroll
    for (int i = 0; i < 32; ++i) {
        int idx = i * 256 + t;
        int hwl = idx >> 7, d = idx & 127;
        int k = bestk[n0 + hwl];
        tile[hwl][d] = embed[(size_t)k * 128 + d];
    }
    __syncthreads();
#pragma unroll
    for (int i = 0; i < 32; ++i) {
        int idx = i * 256 + t;
        int d = idx >> 6, hwl = idx & 63;
        out0[(((size_t)b * D_ + d) << 10) + hw0 + hwl] = tile[hwl][d];
    }
}

extern "C" void kernel_launch(void* const* d_in, const int* in_sizes, int n_in,
                              void* d_out, int out_size, void* d_ws, size_t ws_size,
                              hipStream_t stream) {
    const float* z     = (const float*)d_in[0];
    const float* pw    = (const float*)d_in[1];
    const float* pb    = (const float*)d_in[2];
    const float* embed = (const float*)d_in[3];

    float* out0 = (float*)d_out;
    float* out1 = (float*)d_out + (size_t)B_ * D_ * HW_;

    char* ws = (char*)d_ws;
    float*          zp    = (float*)ws;                                   // 32 MB
    unsigned short* zbf   = (unsigned short*)(ws + (32u << 20));          // 16 MB
    unsigned short* ebf   = (unsigned short*)(ws + (48u << 20));          // 256 KB
    float*          enorm = (float*)(ws + (48u << 20) + (256u << 10));    // 4 KB
    float*          znorm = (float*)(ws + (49u << 20));                   // 256 KB
    int*            bestk = (int*)  (ws + (50u << 20));                   // 256 KB

    hipLaunchKernelGGL(k0_norms,  dim3(4),    dim3(256), 0, stream, embed, enorm, ebf);
    hipLaunchKernelGGL(k1_proj,   dim3(1024), dim3(256), 0, stream, z, pw, pb, zp, zbf, znorm);
    hipLaunchKernelGGL(k2_argmin, dim3(512),  dim3(256), 0, stream,
                       zbf, ebf, zp, embed, enorm, znorm, bestk, out1);
    hipLaunchKernelGGL(k3_gather, dim3(1024), dim3(256), 0, stream, embed, bestk, out0);
}